// Round 4
// baseline (130.927 us; speedup 1.0000x reference)
//
#include <hip/hip_runtime.h>
#include <hip/hip_bf16.h>
#include <math.h>

// Problem constants: B=4, N=256, C=512, H=8, Dh=64
#define BB 4
#define NN 256
#define CC 512
#define HH 8
#define DH 64

typedef __attribute__((ext_vector_type(8))) short bf16x8;
typedef __attribute__((ext_vector_type(4))) float f32x4;
typedef __attribute__((ext_vector_type(2))) float f32x2;

__device__ inline unsigned short f2bf(float f) {
  unsigned u = __float_as_uint(f);
  u += 0x7FFFu + ((u >> 16) & 1u);  // round-to-nearest-even
  return (unsigned short)(u >> 16);
}
__device__ inline float bf2f(unsigned short s) {
  return __uint_as_float((unsigned)s << 16);
}

__device__ inline float4 f4add(float4 a, float4 b) {
  return make_float4(a.x + b.x, a.y + b.y, a.z + b.z, a.w + b.w);
}
__device__ inline float4 f4scale(float4 a, float s) {
  return make_float4(a.x * s, a.y * s, a.z * s, a.w * s);
}

// two fp32 -> packed (hi,lo) bf16 pairs, RNE via v_cvt_pk_bf16_f32
__device__ inline void hilo2(float a, float b, unsigned& hu, unsigned& lu) {
  __hip_bfloat162 h2 = __float22bfloat162_rn(make_float2(a, b));
  float2 hf = __bfloat1622float2(h2);
  __hip_bfloat162 l2 = __float22bfloat162_rn(make_float2(a - hf.x, b - hf.y));
  __builtin_memcpy(&hu, &h2, 4);
  __builtin_memcpy(&lu, &l2, 4);
}
// 8 fp32 (two float4) -> uint4 hi + uint4 lo (8 bf16 each, elem order kept)
__device__ inline void cvt8(float4 f0, float4 f1, uint4& hv, uint4& lv) {
  unsigned h0, h1, h2, h3, l0, l1, l2, l3;
  hilo2(f0.x, f0.y, h0, l0);
  hilo2(f0.z, f0.w, h1, l1);
  hilo2(f1.x, f1.y, h2, l2);
  hilo2(f1.z, f1.w, h3, l3);
  hv = make_uint4(h0, h1, h2, h3);
  lv = make_uint4(l0, l1, l2, l3);
}

// ---------------------------------------------------------------------------
// MFMA GEMM from fp32 operands: C = A * B^T (+bias). The hi/lo bf16 split
// (3 MFMA products) happens IN-REGISTER during LDS staging — no separate
// cvt kernel, no hi/lo HBM round-trip.
// COMBINE: A = (A0 + A1) / (dn0 + dn1 + 1e-6), den indexed per (row, k/64)
//          — folds the attention partial-sum combine + normalize into the
//          projection GEMM's A-staging.
// Structure (verified r3): LDS double-buffer, ONE barrier per K-step.
// 256 thr = 4 waves; tile 64x64; wave -> 32x32 (2x2 mfma 16x16x32). BK=64.
// LDS rows padded to 72 shorts (144B): b128 frags conflict-free. 72KB LDS.
// ---------------------------------------------------------------------------
template <bool COMBINE, bool BIAS>
__global__ __launch_bounds__(256, 2) void gemm_f32(
    const float* __restrict__ A0, const float* __restrict__ A1,
    const float* __restrict__ dn0, const float* __restrict__ dn1,
    const float* __restrict__ Bw, const float* __restrict__ bias,
    float* __restrict__ C, int M, int N, int K) {
  __shared__ unsigned short sAh[2][64][72], sAl[2][64][72];
  __shared__ unsigned short sBh[2][64][72], sBl[2][64][72];
  const int t = threadIdx.x;
  const int lane = t & 63;
  const int w = t >> 6;
  const int bm = blockIdx.y * 64;
  const int bn = blockIdx.x * 64;
  const int wr = (w >> 1) * 32;  // wave row offset in tile
  const int wc = (w & 1) * 32;   // wave col offset
  const int quad = lane >> 4;
  const int l16 = lane & 15;

  // staging: thread t handles rows r0,r1 x dims c8..c8+7
  const int r0 = t >> 3;       // 0..31
  const int r1 = r0 + 32;      // 32..63
  const int c8 = (t & 7) * 8;  // 0..56

  const size_t a0 = (size_t)(bm + r0) * K + c8;
  const size_t a1 = (size_t)(bm + r1) * K + c8;
  const size_t b0 = (size_t)(bn + r0) * K + c8;
  const size_t b1 = (size_t)(bn + r1) * K + c8;

  f32x4 acc[2][2];
#pragma unroll
  for (int i = 0; i < 2; i++)
#pragma unroll
    for (int j = 0; j < 2; j++) {
      acc[i][j][0] = 0.f;
      acc[i][j][1] = 0.f;
      acc[i][j][2] = 0.f;
      acc[i][j][3] = 0.f;
    }

  float4 pa0, pa1, pa2, pa3, pb0, pb1, pb2, pb3;
  float4 qa0, qa1, qa2, qa3;
  float pd0 = 0.f, pd1 = 0.f;

#define GLOADS(K0)                                      \
  pa0 = *(const float4*)(A0 + a0 + (K0));               \
  pa1 = *(const float4*)(A0 + a0 + (K0) + 4);           \
  pa2 = *(const float4*)(A0 + a1 + (K0));               \
  pa3 = *(const float4*)(A0 + a1 + (K0) + 4);           \
  pb0 = *(const float4*)(Bw + b0 + (K0));               \
  pb1 = *(const float4*)(Bw + b0 + (K0) + 4);           \
  pb2 = *(const float4*)(Bw + b1 + (K0));               \
  pb3 = *(const float4*)(Bw + b1 + (K0) + 4);           \
  if (COMBINE) {                                        \
    qa0 = *(const float4*)(A1 + a0 + (K0));             \
    qa1 = *(const float4*)(A1 + a0 + (K0) + 4);         \
    qa2 = *(const float4*)(A1 + a1 + (K0));             \
    qa3 = *(const float4*)(A1 + a1 + (K0) + 4);         \
    const int hd_ = (K0) >> 6;                          \
    pd0 = dn0[(size_t)(bm + r0) * HH + hd_] +           \
          dn1[(size_t)(bm + r0) * HH + hd_];            \
    pd1 = dn0[(size_t)(bm + r1) * HH + hd_] +           \
          dn1[(size_t)(bm + r1) * HH + hd_];            \
  }

#define STOREP(P)                              \
  {                                            \
    float4 fa0 = pa0, fa1 = pa1;               \
    float4 fa2 = pa2, fa3 = pa3;               \
    if (COMBINE) {                             \
      float i0 = 1.f / (pd0 + 1e-6f);          \
      float i1 = 1.f / (pd1 + 1e-6f);          \
      fa0 = f4scale(f4add(fa0, qa0), i0);      \
      fa1 = f4scale(f4add(fa1, qa1), i0);      \
      fa2 = f4scale(f4add(fa2, qa2), i1);      \
      fa3 = f4scale(f4add(fa3, qa3), i1);      \
    }                                          \
    uint4 hv, lv;                              \
    cvt8(fa0, fa1, hv, lv);                    \
    *(uint4*)&sAh[P][r0][c8] = hv;             \
    *(uint4*)&sAl[P][r0][c8] = lv;             \
    cvt8(fa2, fa3, hv, lv);                    \
    *(uint4*)&sAh[P][r1][c8] = hv;             \
    *(uint4*)&sAl[P][r1][c8] = lv;             \
    cvt8(pb0, pb1, hv, lv);                    \
    *(uint4*)&sBh[P][r0][c8] = hv;             \
    *(uint4*)&sBl[P][r0][c8] = lv;             \
    cvt8(pb2, pb3, hv, lv);                    \
    *(uint4*)&sBh[P][r1][c8] = hv;             \
    *(uint4*)&sBl[P][r1][c8] = lv;             \
  }

  GLOADS(0)
  STOREP(0)
  __syncthreads();
  GLOADS(64)

  int p = 0;
  for (int k0 = 0; k0 < K; k0 += 64) {
#pragma unroll
    for (int kk = 0; kk < 2; kk++) {
      const int kc = kk * 32 + quad * 8;
      bf16x8 ah[2], al[2], bh[2], bl[2];
#pragma unroll
      for (int i = 0; i < 2; i++) {
        ah[i] = *(const bf16x8*)&sAh[p][wr + i * 16 + l16][kc];
        al[i] = *(const bf16x8*)&sAl[p][wr + i * 16 + l16][kc];
        bh[i] = *(const bf16x8*)&sBh[p][wc + i * 16 + l16][kc];
        bl[i] = *(const bf16x8*)&sBl[p][wc + i * 16 + l16][kc];
      }
#pragma unroll
      for (int i = 0; i < 2; i++)
#pragma unroll
        for (int j = 0; j < 2; j++) {
          acc[i][j] = __builtin_amdgcn_mfma_f32_16x16x32_bf16(
              ah[i], bh[j], acc[i][j], 0, 0, 0);
          acc[i][j] = __builtin_amdgcn_mfma_f32_16x16x32_bf16(
              ah[i], bl[j], acc[i][j], 0, 0, 0);
          acc[i][j] = __builtin_amdgcn_mfma_f32_16x16x32_bf16(
              al[i], bh[j], acc[i][j], 0, 0, 0);
        }
    }
    if (k0 + 64 < K) {
      STOREP(p ^ 1)
      if (k0 + 128 < K) {
        GLOADS(k0 + 128)
      }
    }
    __syncthreads();
    p ^= 1;
  }
#undef GLOADS
#undef STOREP

  // epilogue: C/D layout col=lane&15, row=quad*4+reg (verified m89/m91)
#pragma unroll
  for (int i = 0; i < 2; i++)
#pragma unroll
    for (int j = 0; j < 2; j++) {
      int n = bn + wc + j * 16 + l16;
      float bv = BIAS ? bias[n] : 0.f;
#pragma unroll
      for (int r = 0; r < 4; r++) {
        int m = bm + wr + i * 16 + quad * 4 + r;
        C[(size_t)m * N + n] = acc[i][j][r] + bv;
      }
    }
}

// ---------------------------------------------------------------------------
// Fused Fourier attention v5: KEY-SPLIT for occupancy.
// Grid (x = b*8+h [32], y = qc*2+kc [32]); 512 thr = 8 waves.
// Each block handles 16 queries x 128 keys (2 tiles of 64), writes PARTIAL
// fp32 numerator (num[kc]) and denominator (den[kc]); the combine+normalize
// is folded into gemm2's A-staging. 1024 blocks -> 3 resident/CU (LDS cap),
// 24 waves/CU (was 512 blocks = 2/CU, 16 waves).
// XCD locality: linear dispatch id % 8 = blockIdx.x % 8 = h, so all 32
// blocks sharing one (b,h)'s K/V slab land on one XCD's L2.
// Score math identical to r3 (passing, eps-ordering collision-safe).
// AV via MFMA on hi/lo bf16 P tile; s_setprio(1) around the MFMA cluster.
// ---------------------------------------------------------------------------
__global__ __launch_bounds__(512, 6) void fourier_attn(
    const float* __restrict__ qkv, const float* __restrict__ paramR,
    float* __restrict__ num0, float* __restrict__ num1,
    float* __restrict__ den0, float* __restrict__ den1) {
  __shared__ float Kt[64][68];            // K tile, row-major, padded
  __shared__ float Vs[64][68];            // V tile, row-major, padded
  __shared__ float Qs[16][64];            // staged queries (broadcast reads)
  __shared__ unsigned short Pah[16][72];  // a4 hi (bf16), padded 144B rows
  __shared__ unsigned short Pal[16][72];  // a4 lo
  __shared__ f32x4 Red[4][64];            // cross-wave partial sums

  const int t = threadIdx.x;
  const int lane = t & 63;
  const int wv = t >> 6;  // 0..7
  const int quad = lane >> 4;
  const int l16 = lane & 15;
  const int h = blockIdx.x & 7;
  const int b = blockIdx.x >> 3;
  const int qc = blockIdx.y >> 1;
  const int kc = blockIdx.y & 1;  // key half: tiles kc*2 .. kc*2+1
  const float R = paramR[0];
  const float cR = R * 0.15915494309189535f;  // R / (2*pi)

  const float* base = qkv + (size_t)b * NN * (3 * CC) + h * DH;

  if (t < 256) {
    int r = t >> 4;
    int c4 = (t & 15) << 2;
    *(float4*)&Qs[r][c4] =
        *(const float4*)(base + (size_t)(qc * 16 + r) * (3 * CC) + c4);
  }

  const int qi0 = wv * 2, qi1 = wv * 2 + 1;
  float Sp[2] = {0.f, 0.f};
  f32x4 oacc;
  oacc[0] = 0.f; oacc[1] = 0.f; oacc[2] = 0.f; oacc[3] = 0.f;

  // AV-phase role of this wave: dims chunk nc, key-half-within-tile g2
  const int nc = wv & 3;
  const int g2 = wv >> 2;
  const int kb = g2 * 32 + quad * 8;

  // prefetch registers for one K/V tile (2 float4 each)
  float4 pk[2], pv[2];
#define LOADT(JT)                                                   \
  _Pragma("unroll") for (int u0 = 0; u0 < 2; u0++) {                \
    int u = t + 512 * u0;                                           \
    int r_ = u >> 4;                                                \
    int c4_ = (u & 15) << 2;                                        \
    const float* row_ = base + (size_t)((JT) * 64 + r_) * (3 * CC); \
    pk[u0] = *(const float4*)(row_ + CC + c4_);                     \
    pv[u0] = *(const float4*)(row_ + 2 * CC + c4_);                 \
  }

  LOADT(kc * 2)

  const f32x2 eps2 = {1e-30f, 1e-30f};
  const f32x2 cR2 = {cR, cR};

  for (int jj = 0; jj < 2; jj++) {
    __syncthreads();  // B1: prev tile's AV reads of Vs/Pah done
#pragma unroll
    for (int u0 = 0; u0 < 2; u0++) {
      int u = t + 512 * u0;
      int r = u >> 4;          // key row
      int c4 = (u & 15) << 2;  // dim
      *(float4*)&Kt[r][c4] = pk[u0];
      *(float4*)&Vs[r][c4] = pv[u0];
    }
    __syncthreads();  // B2: staged tile (and Qs on jj=0) ready
    if (jj == 0) {
      LOADT(kc * 2 + 1)  // in flight across score+AV below
    }

    // ---- score phase: lane = key, packed f32x2 math
    f32x2 nmA0 = {1.f, 1.f}, nmB0 = {1.f, 1.f};
    f32x2 nmA1 = {1.f, 1.f}, nmB1 = {1.f, 1.f};
    f32x2 dnA0 = {1.f, 1.f}, dnB0 = {1.f, 1.f};
    f32x2 dnA1 = {1.f, 1.f}, dnB1 = {1.f, 1.f};
#pragma unroll
    for (int d4 = 0; d4 < 16; d4++) {
      float4 k4 = *(const float4*)&Kt[lane][4 * d4];
      float4 qa = *(const float4*)&Qs[qi0][4 * d4];
      float4 qb = *(const float4*)&Qs[qi1][4 * d4];
      f32x2 kA = {k4.x, k4.y};
      f32x2 kB = {k4.z, k4.w};
      // (q - k) FIRST, then + eps: collision-safe (r2 NaN post-mortem)
      f32x2 dA0 = ((f32x2){qa.x, qa.y} - kA) + eps2;
      f32x2 dB0 = ((f32x2){qa.z, qa.w} - kB) + eps2;
      f32x2 dA1 = ((f32x2){qb.x, qb.y} - kA) + eps2;
      f32x2 dB1 = ((f32x2){qb.z, qb.w} - kB) + eps2;
      f32x2 gA0 = cR2 * dA0, gB0 = cR2 * dB0;
      f32x2 gA1 = cR2 * dA1, gB1 = cR2 * dB1;
      f32x2 sA0, sB0, sA1, sB1;
      sA0.x = __builtin_amdgcn_sinf(gA0.x);
      sA0.y = __builtin_amdgcn_sinf(gA0.y);
      sB0.x = __builtin_amdgcn_sinf(gB0.x);
      sB0.y = __builtin_amdgcn_sinf(gB0.y);
      sA1.x = __builtin_amdgcn_sinf(gA1.x);
      sA1.y = __builtin_amdgcn_sinf(gA1.y);
      sB1.x = __builtin_amdgcn_sinf(gB1.x);
      sB1.y = __builtin_amdgcn_sinf(gB1.y);
      nmA0 *= sA0;
      nmB0 *= sB0;
      nmA1 *= sA1;
      nmB1 *= sB1;
      dnA0 *= dA0;
      dnB0 *= dB0;
      dnA1 *= dA1;
      dnB1 *= dB1;
    }
    {
      f32x2 n0 = nmA0 * nmB0, d0 = dnA0 * dnB0;
      f32x2 n1 = nmA1 * nmB1, d1 = dnA1 * dnB1;
      float sc0 = (n0.x * n0.y) / (d0.x * d0.y);
      float sc1 = (n1.x * n1.y) / (d1.x * d1.y);
      float t0 = sc0 * sc0, t1 = sc1 * sc1;
      float a40 = t0 * t0, a41 = t1 * t1;
      Sp[0] += a40;
      Sp[1] += a41;
      unsigned short h0 = f2bf(a40), h1 = f2bf(a41);
      Pah[qi0][lane] = h0;
      Pal[qi0][lane] = f2bf(a40 - bf2f(h0));
      Pah[qi1][lane] = h1;
      Pal[qi1][lane] = f2bf(a41 - bf2f(h1));
    }
    __syncthreads();  // B3: P tile complete

    // ---- AV phase: one 16x16x32 MFMA triple per wave
    {
      bf16x8 pah = *(const bf16x8*)&Pah[l16][kb];
      bf16x8 pal = *(const bf16x8*)&Pal[l16][kb];
      bf16x8 vh, vl;
#pragma unroll
      for (int j = 0; j < 8; j++) {
        float f = Vs[kb + j][nc * 16 + l16];
        unsigned short hb = f2bf(f);
        vh[j] = (short)hb;
        vl[j] = (short)f2bf(f - bf2f(hb));
      }
      __builtin_amdgcn_s_setprio(1);
      oacc = __builtin_amdgcn_mfma_f32_16x16x32_bf16(pah, vh, oacc, 0, 0, 0);
      oacc = __builtin_amdgcn_mfma_f32_16x16x32_bf16(pah, vl, oacc, 0, 0, 0);
      oacc = __builtin_amdgcn_mfma_f32_16x16x32_bf16(pal, vh, oacc, 0, 0, 0);
      __builtin_amdgcn_s_setprio(0);
    }
  }
#undef LOADT

  // ---- finalize: write partial den (per query) + partial num (fp32)
  float* nump = kc ? num1 : num0;
  float* denp = kc ? den1 : den0;
#pragma unroll
  for (int q = 0; q < 2; q++) {
    float s = Sp[q];
#pragma unroll
    for (int off = 32; off > 0; off >>= 1) s += __shfl_xor(s, off, 64);
    if (lane == 0) {
      int m = b * NN + qc * 16 + qi0 + q;
      denp[(size_t)m * HH + h] = s;
    }
  }
  if (wv >= 4) Red[wv - 4][lane] = oacc;
  __syncthreads();
  if (wv < 4) {
    f32x4 part = Red[wv][lane];
#pragma unroll
    for (int r = 0; r < 4; r++) {
      int q = quad * 4 + r;
      int m = b * NN + qc * 16 + q;
      nump[(size_t)m * CC + h * DH + nc * 16 + l16] = oacc[r] + part[r];
    }
  }
}

// ---------------------------------------------------------------------------
extern "C" void kernel_launch(void* const* d_in, const int* in_sizes, int n_in,
                              void* d_out, int out_size, void* d_ws,
                              size_t ws_size, hipStream_t stream) {
  const float* x = (const float*)d_in[0];       // (B,N,C)
  const float* w_qkv = (const float*)d_in[1];   // (3C, C)
  const float* w_proj = (const float*)d_in[2];  // (C, C)
  const float* b_proj = (const float*)d_in[3];  // (C,)
  const float* paramR = (const float*)d_in[4];  // (1,)
  float* outp = (float*)d_out;                  // (B,N,C)

  const int nX = BB * NN * CC;  // 524288 (= M*C elements)

  // ws layout (fp32, all 16B-aligned): qkv | num0 | num1 | den0 | den1
  float* qkv_ws = (float*)d_ws;            // 1024*1536
  float* num0 = qkv_ws + 1024 * 1536;      // 1024*512
  float* num1 = num0 + nX;                 // 1024*512
  float* den0 = num1 + nX;                 // 1024*8
  float* den1 = den0 + 1024 * HH;          // 1024*8

  // 1) qkv = x @ w_qkv^T : M=1024, N=1536, K=512 (24x16 = 384 blocks);
  //    fp32 operands, hi/lo split in staging (no cvt kernel).
  gemm_f32<false, false><<<dim3(3 * CC / 64, BB * NN / 64), 256, 0, stream>>>(
      x, nullptr, nullptr, nullptr, w_qkv, nullptr, qkv_ws, BB * NN, 3 * CC,
      CC);

  // 2) fused fourier attention, key-split 2-way -> partial num/den (fp32)
  fourier_attn<<<dim3(HH * BB, (NN / 16) * 2), 512, 0, stream>>>(
      qkv_ws, paramR, num0, num1, den0, den1);

  // 3) out = ((num0+num1)/(den0+den1+eps)) @ w_proj^T + b_proj :
  //    M=1024, N=512, K=512 (8x16 = 128 blocks); combine in A-staging.
  gemm_f32<true, true><<<dim3(CC / 64, BB * NN / 64), 256, 0, stream>>>(
      num0, num1, den0, den1, w_proj, b_proj, outp, BB * NN, CC, CC);
}